// Round 12
// baseline (293.914 us; speedup 1.0000x reference)
//
#include <hip/hip_runtime.h>
#include <math.h>

#define SEQ  1024
#define DM   1024
#define NHD  8
#define DQKD 64
#define DVD  128
#define QKD  512
#define VD   1024
#define NB   2
#define VOC  2048   // vob row stride: v(1024) | o(1024)

typedef __attribute__((ext_vector_type(8))) short bf16x8;
typedef __attribute__((ext_vector_type(4))) float f32x4;

__device__ __forceinline__ float softcap(float t) {
    return 15.0f * tanhf(t * (1.0f / 15.0f));
}

__device__ __forceinline__ unsigned short f2bf(float f) {
    union { float f; unsigned u; } v; v.f = f;
    unsigned r = v.u + 0x7FFFu + ((v.u >> 16) & 1u);   // round-to-nearest-even
    return (unsigned short)(r >> 16);
}

// ---------------- fused fp32 -> bf16 convert: 4 segments in one launch ----------------
// seg0: x (2048 blk) | seg1: Wv (1024) | seg2: Wog (1024) | seg3: Wout (1024)
__global__ __launch_bounds__(256) void cvt4_kernel(
    const float* __restrict__ s0, unsigned short* __restrict__ d0,
    const float* __restrict__ s1, unsigned short* __restrict__ d1,
    const float* __restrict__ s2, unsigned short* __restrict__ d2,
    const float* __restrict__ s3, unsigned short* __restrict__ d3) {
    int bx = blockIdx.x;
    const float* s; unsigned short* d; int i;
    if (bx < 2048)      { s = s0; d = d0; i = bx * 256 + threadIdx.x; }
    else if (bx < 3072) { s = s1; d = d1; i = (bx - 2048) * 256 + threadIdx.x; }
    else if (bx < 4096) { s = s2; d = d2; i = (bx - 3072) * 256 + threadIdx.x; }
    else                { s = s3; d = d3; i = (bx - 4096) * 256 + threadIdx.x; }
    float4 v = ((const float4*)s)[i];
    ushort4 o;
    o.x = f2bf(v.x); o.y = f2bf(v.y); o.z = f2bf(v.z); o.w = f2bf(v.w);
    ((ushort4*)d)[i] = o;
}

// ---------------- gates: i_pre/f_pre = softcap(x @ W^T + b), layout [b,h,t] ----------------
__global__ __launch_bounds__(256) void gates_kernel(
    const float* __restrict__ x,
    const float* __restrict__ Wi, const float* __restrict__ bi,
    const float* __restrict__ Wf, const float* __restrict__ bf,
    float* __restrict__ ipre, float* __restrict__ fpre) {
    int wid = threadIdx.x >> 6, lane = threadIdx.x & 63;
    int row = blockIdx.x * 4 + wid;          // 0..2047 = b*SEQ + t
    int b = row >> 10, t = row & 1023;
    const float* xr = x + (size_t)row * DM;
    float ai[NHD] = {}, af[NHD] = {};
    for (int d = lane; d < DM; d += 64) {
        float xv = xr[d];
#pragma unroll
        for (int h = 0; h < NHD; ++h) {
            ai[h] = fmaf(xv, Wi[h * DM + d], ai[h]);
            af[h] = fmaf(xv, Wf[h * DM + d], af[h]);
        }
    }
#pragma unroll
    for (int h = 0; h < NHD; ++h) {
        for (int off = 32; off > 0; off >>= 1) {
            ai[h] += __shfl_xor(ai[h], off);
            af[h] += __shfl_xor(af[h], off);
        }
    }
    if (lane == 0) {
#pragma unroll
        for (int h = 0; h < NHD; ++h) {
            ipre[((b * NHD + h) << 10) + t] = softcap(ai[h] + bi[h]);
            fpre[((b * NHD + h) << 10) + t] = softcap(af[h] + bf[h]);
        }
    }
}

// ---------------- per-(b,h) scans via wave shfl + cross-wave combine (3 barriers) ----------------
__global__ __launch_bounds__(1024) void scan_kernel(
    const float* __restrict__ ipre, const float* __restrict__ fpre,
    float* __restrict__ gv, float* __restrict__ Mrow,
    float* __restrict__ sufg, float* __restrict__ expnegm) {
    __shared__ float ws1[16], ws2[16], ws3[16];
    int t = threadIdx.x, bh = blockIdx.x;
    int base = bh << 10;
    int lane = t & 63, wid = t >> 6;
    // inclusive prefix sum of f -> cumF
    float s = fpre[base + t];
#pragma unroll
    for (int off = 1; off < 64; off <<= 1) {
        float o = __shfl_up(s, off);
        if (lane >= off) s += o;
    }
    if (lane == 63) ws1[wid] = s;
    __syncthreads();
    float bsum = 0.0f;
#pragma unroll
    for (int w = 0; w < 16; ++w) { float v = ws1[w]; if (w < wid) bsum += v; }
    float cumF = s + bsum;
    float g = ipre[base + t] - cumF;
    gv[base + t] = g;
    // inclusive prefix max of g
    float m = g;
#pragma unroll
    for (int off = 1; off < 64; off <<= 1) {
        float o = __shfl_up(m, off);
        if (lane >= off) m = fmaxf(m, o);
    }
    if (lane == 63) ws2[wid] = m;
    __syncthreads();
    float bmax = -1e30f;
#pragma unroll
    for (int w = 0; w < 16; ++w) { float v = ws2[w]; if (w < wid) bmax = fmaxf(bmax, v); }
    float Mt = fmaxf(0.0f, fmaxf(m, bmax));   // include initial-state path (m0 = 0)
    Mrow[base + t] = Mt;
    expnegm[base + t] = expf(-(cumF + Mt));   // exp(-m_t)
    // inclusive suffix max of g
    float sm = g;
#pragma unroll
    for (int off = 1; off < 64; off <<= 1) {
        float o = __shfl_down(sm, off);
        if (lane + off < 64) sm = fmaxf(sm, o);
    }
    if (lane == 0) ws3[wid] = sm;
    __syncthreads();
    float amax = -1e30f;
#pragma unroll
    for (int w = 0; w < 16; ++w) { float v = ws3[w]; if (w > wid) amax = fmaxf(amax, v); }
    sufg[base + t] = fmaxf(sm, amax);
}

// ---------------- q/k projection GEMM: fp32, 512 threads (occupancy-tuned) ----------------
// conditioning-critical path: bf16 q/k caused the round-6 1.109 failure (qn cancellation)
#define QBM 64
#define QBN 64
#define QBK 16
__global__ __launch_bounds__(512) void qk_gemm_kernel(
    const float* __restrict__ x,
    const float* __restrict__ Wq, const float* __restrict__ Wk,
    float* __restrict__ qb, float* __restrict__ kb) {
    __shared__ __align__(16) float As[QBK][QBM + 4];
    __shared__ __align__(16) float Bs[QBK][QBN + 4];
    int bx = blockIdx.x;                 // 0..15: 8 q-tiles, 8 k-tiles
    const float* W; float* C; int col0;
    if (bx < 8) { W = Wq; C = qb; col0 = bx * QBN; }
    else        { W = Wk; C = kb; col0 = (bx - 8) * QBN; }
    int tid = threadIdx.x;
    int row0 = blockIdx.y * QBM;
    int tx = tid & 15, ty = tid >> 4;          // ty 0..31: 2 rows each; tx: 4 cols each
    int sr = (tid & 255) >> 2, sc = tid & 3;   // staging: waves 0-3 -> A, waves 4-7 -> B
    bool stageA = tid < 256;
    const float* P = stageA ? x + (size_t)(row0 + sr) * DM + sc * 4
                            : W + (size_t)(col0 + sr) * DM + sc * 4;
    float acc[2][4] = {};
    for (int k0 = 0; k0 < DM; k0 += QBK) {
        float4 v4 = *(const float4*)(P + k0);
        if (stageA) {
            As[sc * 4 + 0][sr] = v4.x; As[sc * 4 + 1][sr] = v4.y;
            As[sc * 4 + 2][sr] = v4.z; As[sc * 4 + 3][sr] = v4.w;
        } else {
            Bs[sc * 4 + 0][sr] = v4.x; Bs[sc * 4 + 1][sr] = v4.y;
            Bs[sc * 4 + 2][sr] = v4.z; Bs[sc * 4 + 3][sr] = v4.w;
        }
        __syncthreads();
#pragma unroll
        for (int kk = 0; kk < QBK; ++kk) {
            float a0 = As[kk][ty * 2 + 0];
            float a1 = As[kk][ty * 2 + 1];
            float4 bv = *(const float4*)(&Bs[kk][tx * 4]);
            float br[4] = {bv.x, bv.y, bv.z, bv.w};
#pragma unroll
            for (int j = 0; j < 4; ++j) {
                acc[0][j] = fmaf(a0, br[j], acc[0][j]);
                acc[1][j] = fmaf(a1, br[j], acc[1][j]);
            }
        }
        __syncthreads();
    }
#pragma unroll
    for (int i = 0; i < 2; ++i) {
        float4 o4 = {acc[i][0], acc[i][1], acc[i][2], acc[i][3]};
        *(float4*)(C + (size_t)(row0 + ty * 2 + i) * QKD + col0 + tx * 4) = o4;
    }
}

// ---------------- bf16 MFMA NT GEMM: C[M][ldc] = A[M][K] . B[ldc-rows][K]^T ----------------
// m97 structure: 128x128 tile, BK=32, 4 waves (2x2), global_load_lds w=16, single LDS buf.
__global__ __launch_bounds__(256) void mfma_nt_kernel(
    const unsigned short* __restrict__ A, const unsigned short* __restrict__ B,
    float* __restrict__ C, int ldc, int K) {
    __shared__ __align__(16) unsigned short As[128 * 32];
    __shared__ __align__(16) unsigned short Bs[128 * 32];
    int tid = threadIdx.x;
    int w = tid >> 6, l = tid & 63;
    int wr = w >> 1, wc = w & 1;
    int r0 = blockIdx.y * 128, c0 = blockIdx.x * 128;
    f32x4 acc[4][4] = {};
    for (int k0 = 0; k0 < K; k0 += 32) {
#pragma unroll
        for (int it = 0; it < 2; ++it) {
            const unsigned short* ga = A + (size_t)(r0 + it * 64 + w * 16 + (l >> 2)) * K + k0 + ((l & 3) << 3);
            __builtin_amdgcn_global_load_lds(
                (const __attribute__((address_space(1))) unsigned int*)ga,
                (__attribute__((address_space(3))) unsigned int*)&As[(it * 64 + w * 16) * 32],
                16, 0, 0);
            const unsigned short* gb = B + (size_t)(c0 + it * 64 + w * 16 + (l >> 2)) * K + k0 + ((l & 3) << 3);
            __builtin_amdgcn_global_load_lds(
                (const __attribute__((address_space(1))) unsigned int*)gb,
                (__attribute__((address_space(3))) unsigned int*)&Bs[(it * 64 + w * 16) * 32],
                16, 0, 0);
        }
        __syncthreads();   // drains vmcnt before any wave reads LDS
        bf16x8 af[4], bfr[4];
#pragma unroll
        for (int mi = 0; mi < 4; ++mi)
            af[mi] = *(const bf16x8*)&As[(wr * 64 + mi * 16 + (l & 15)) * 32 + ((l >> 4) << 3)];
#pragma unroll
        for (int ni = 0; ni < 4; ++ni)
            bfr[ni] = *(const bf16x8*)&Bs[(wc * 64 + ni * 16 + (l & 15)) * 32 + ((l >> 4) << 3)];
#pragma unroll
        for (int mi = 0; mi < 4; ++mi)
#pragma unroll
            for (int ni = 0; ni < 4; ++ni)
                acc[mi][ni] = __builtin_amdgcn_mfma_f32_16x16x32_bf16(af[mi], bfr[ni], acc[mi][ni], 0, 0, 0);
        __syncthreads();   // protect LDS from next stage
    }
    // C/D layout (m89/m91): col = lane&15, row = (lane>>4)*4 + reg
#pragma unroll
    for (int mi = 0; mi < 4; ++mi) {
#pragma unroll
        for (int ni = 0; ni < 4; ++ni) {
            int row = r0 + wr * 64 + mi * 16 + ((l >> 4) << 2);
            int col = c0 + wc * 64 + ni * 16 + (l & 15);
            float* cp = C + (size_t)row * ldc + col;
#pragma unroll
            for (int j = 0; j < 4; ++j) cp[(size_t)j * ldc] = acc[mi][ni][j];
        }
    }
}

// ---------------- windowed causal "attention" replacing the scan ----------------
__global__ __launch_bounds__(256) void attn_kernel(
    const float* __restrict__ q, const float* __restrict__ k,
    const float* __restrict__ vob, const float* __restrict__ gv,
    const float* __restrict__ Mrow, const float* __restrict__ sufg,
    const float* __restrict__ expnegm, float* __restrict__ hbuf) {
    int wid = threadIdx.x >> 6, lane = threadIdx.x & 63;
    int bh = blockIdx.x;                 // 0..15
    int t = blockIdx.y * 4 + wid;        // 0..1023
    int b = bh >> 3, h = bh & 7;
    int base = bh << 10;
    float Mt = Mrow[base + t];
    float qs = q[(size_t)(b * SEQ + t) * QKD + h * DQKD + lane] * 0.125f;
    float num0 = 0.0f, num1 = 0.0f, qn = 0.0f;
    for (int j = 0; j <= t; ++j) {
        if ((j & 15) == 0) {
            if (sufg[base + j] - Mt < -60.0f) break;   // all remaining weights < e^-60
        }
        float kj = k[(size_t)(b * SEQ + j) * QKD + h * DQKD + lane];
        float s = qs * kj;
#pragma unroll
        for (int off = 32; off > 0; off >>= 1) s += __shfl_xor(s, off);
        float w = expf(gv[base + j] - Mt);
        float p = w * s;
        qn += p;
        const float* vr = vob + (size_t)(b * SEQ + j) * VOC + h * DVD;
        num0 = fmaf(p, vr[lane], num0);
        num1 = fmaf(p, vr[lane + 64], num1);
    }
    float denom = fmaxf(fabsf(qn), expnegm[base + t]) + 1e-6f;
    float* hr = hbuf + (size_t)(b * SEQ + t) * VD + h * DVD;
    hr[lane] = num0 / denom;
    hr[lane + 64] = num1 / denom;
}

// ---------------- layernorm over NH*DV + sigmoid output gate, emit bf16 ----------------
__global__ __launch_bounds__(256) void ln_gate_kernel(
    const float* __restrict__ hbuf, const float* __restrict__ vob,
    const float* __restrict__ lnw, const float* __restrict__ lnb,
    unsigned short* __restrict__ hgbf) {
    int row = blockIdx.x, tid = threadIdx.x;
    float4 hv = ((const float4*)(hbuf + (size_t)row * VD))[tid];
    float s1 = hv.x + hv.y + hv.z + hv.w;
    float s2 = hv.x * hv.x + hv.y * hv.y + hv.z * hv.z + hv.w * hv.w;
    for (int off = 32; off > 0; off >>= 1) {
        s1 += __shfl_xor(s1, off);
        s2 += __shfl_xor(s2, off);
    }
    __shared__ float w1[4], w2[4];
    int wid = tid >> 6, lane = tid & 63;
    if (lane == 0) { w1[wid] = s1; w2[wid] = s2; }
    __syncthreads();
    s1 = w1[0] + w1[1] + w1[2] + w1[3];
    s2 = w2[0] + w2[1] + w2[2] + w2[3];
    float mean = s1 * (1.0f / 1024.0f);
    float var = s2 * (1.0f / 1024.0f) - mean * mean;
    float rs = rsqrtf(var + 1e-6f);
    float4 ov = ((const float4*)(vob + (size_t)row * VOC + VD))[tid];   // o-gate half
    float4 wv = ((const float4*)lnw)[tid];
    float4 bv = ((const float4*)lnb)[tid];
    float ox = (1.0f / (1.0f + expf(-ov.x))) * ((hv.x - mean) * rs * wv.x + bv.x);
    float oy = (1.0f / (1.0f + expf(-ov.y))) * ((hv.y - mean) * rs * wv.y + bv.y);
    float oz = (1.0f / (1.0f + expf(-ov.z))) * ((hv.z - mean) * rs * wv.z + bv.z);
    float ow = (1.0f / (1.0f + expf(-ov.w))) * ((hv.w - mean) * rs * wv.w + bv.w);
    ushort4 o4;
    o4.x = f2bf(ox); o4.y = f2bf(oy); o4.z = f2bf(oz); o4.w = f2bf(ow);
    ((ushort4*)(hgbf + (size_t)row * VD))[tid] = o4;
}

extern "C" void kernel_launch(void* const* d_in, const int* in_sizes, int n_in,
                              void* d_out, int out_size, void* d_ws, size_t ws_size,
                              hipStream_t stream) {
    const float* x    = (const float*)d_in[0];
    const float* Wq   = (const float*)d_in[1];
    const float* Wk   = (const float*)d_in[2];
    const float* Wv   = (const float*)d_in[3];
    const float* Wog  = (const float*)d_in[4];
    const float* Wi   = (const float*)d_in[5];
    const float* bi   = (const float*)d_in[6];
    const float* Wf   = (const float*)d_in[7];
    const float* bf   = (const float*)d_in[8];
    const float* lnw  = (const float*)d_in[9];
    const float* lnb  = (const float*)d_in[10];
    const float* Wout = (const float*)d_in[11];
    float* out = (float*)d_out;

    float* ws = (float*)d_ws;
    const size_t BH   = (size_t)NB * NHD * SEQ;      // 16384
    const size_t ROWS = (size_t)NB * SEQ;            // 2048
    // Plain layout, ~40.3 MB (round 6 proved ws_size >= 44.5 MB). No aliasing except hb=out.
    float* ipre = ws;                                // 6 x [16,1024]
    float* fpre = ipre + BH;
    float* gv   = fpre + BH;
    float* Mrow = gv + BH;
    float* sufg = Mrow + BH;
    float* enm  = sufg + BH;
    float* qb   = enm + BH;                          // [2048, 512]  fp32
    float* kb   = qb + ROWS * QKD;                   // [2048, 512]  fp32
    float* vob  = kb + ROWS * QKD;                   // [2048, 2048] fp32
    unsigned short* xbf   = (unsigned short*)(vob + ROWS * VOC);  // [2048,1024] bf16
    unsigned short* Wvobf = xbf + ROWS * DM;                      // [2048,1024] bf16 (Wv|Wog)
    unsigned short* Wobf  = Wvobf + (size_t)VOC * DM;             // [1024,1024] bf16
    unsigned short* hgbf  = Wobf + (size_t)DM * VD;               // [2048,1024] bf16
    float* hb = out;   // attn fully writes d_out; ln reads; out-mfma overwrites (proven r10/r11)

    // 1. all fp32->bf16 conversions in one launch
    cvt4_kernel<<<5120, 256, 0, stream>>>(x, xbf,
                                          Wv, Wvobf,
                                          Wog, Wvobf + (size_t)VD * DM,
                                          Wout, Wobf);
    gates_kernel<<<512, 256, 0, stream>>>(x, Wi, bi, Wf, bf, ipre, fpre);
    scan_kernel<<<16, 1024, 0, stream>>>(ipre, fpre, gv, Mrow, sufg, enm);
    // 2. v|o = xbf . Wvobf^T : [2048, 2048]
    mfma_nt_kernel<<<dim3(VOC / 128, ROWS / 128), 256, 0, stream>>>(xbf, Wvobf, vob, VOC, DM);
    // 3. q,k fp32 (conditioning-critical)
    qk_gemm_kernel<<<dim3(16, ROWS / QBM), 512, 0, stream>>>(x, Wq, Wk, qb, kb);
    // 4. windowed attention
    attn_kernel<<<dim3(16, SEQ / 4), 256, 0, stream>>>(qb, kb, vob, gv, Mrow, sufg, enm, hb);
    // 5. LN + sigmoid gate -> bf16
    ln_gate_kernel<<<ROWS, 256, 0, stream>>>(hb, vob, lnw, lnb, hgbf);
    // 6. out = hgbf . Wobf^T : [2048, 1024]
    mfma_nt_kernel<<<dim3(DM / 128, ROWS / 128), 256, 0, stream>>>(hgbf, Wobf, out, DM, VD);
}